// Round 1
// 339.204 us; speedup vs baseline: 1.1048x; 1.1048x over previous
//
#include <hip/hip_runtime.h>
#include <math.h>

// Problem shape (fixed by setup_inputs)
constexpr int Bn = 8, Dn = 64, Hn = 256, Wn = 512;
constexpr int HW   = Hn * Wn;        // 131072
constexpr int NPIX = Bn * HW;        // 1048576
constexpr int TPB  = 256;
constexpr int PPT  = 4;              // pixels per thread (float4)
constexpr int NBLK = NPIX / (TPB * PPT); // 1024

typedef float v4f __attribute__((ext_vector_type(4)));

// entropy(p) = log(sum_d exp(sim_d)) - (sum_d T_d * sim_d) / (sum_d T_d)
// with T_d = exp(-|gt - 2d|). The Laplace 1/(2*DIVERSITY) factor cancels.
// Each block writes its partial (sum, count) to ws[blockIdx.x] -> no memset,
// no atomics; sce_final reduces the 1024 partials.
__global__ __launch_bounds__(TPB) void sce_main(const float* __restrict__ sim,
                                                const float* __restrict__ gt,
                                                float2* __restrict__ partial) {
    const int tid = blockIdx.x * TPB + threadIdx.x;
    const int p0  = tid * PPT;               // first pixel handled by this thread
    const int b   = p0 / HW;
    const int rem = p0 - b * HW;             // contiguous within a batch image
    const v4f* simv = reinterpret_cast<const v4f*>(sim + (size_t)b * Dn * HW + rem);
    const int dstride = HW / 4;              // float4 stride between d planes

    const v4f g4 = __builtin_nontemporal_load(reinterpret_cast<const v4f*>(gt + p0));
    float gg[4] = {g4[0], g4[1], g4[2], g4[3]};

    float s[4]  = {0.f, 0.f, 0.f, 0.f};      // sum exp(sim)
    float S1[4] = {0.f, 0.f, 0.f, 0.f};      // sum T
    float S2[4] = {0.f, 0.f, 0.f, 0.f};      // sum T * sim

#pragma unroll 16
    for (int d = 0; d < Dn; ++d) {
        v4f v4 = __builtin_nontemporal_load(simv + (size_t)d * dstride); // nt: streamed once
        float v[4] = {v4[0], v4[1], v4[2], v4[3]};
        const float dd = 2.0f * (float)d;        // DISPARITY_STEP * d
#pragma unroll
        for (int i = 0; i < 4; ++i) {
            s[i] += __expf(v[i]);
            float t = __expf(-fabsf(gg[i] - dd));
            S1[i] += t;
            S2[i] = fmaf(t, v[i], S2[i]);
        }
    }

    float lsum = 0.0f, lcnt = 0.0f;
#pragma unroll
    for (int i = 0; i < 4; ++i) {
        if (isfinite(gg[i])) {                   // unknown gt = inf -> skip
            lsum += logf(s[i]) - S2[i] / S1[i];
            lcnt += 1.0f;
        }
    }

    // wave (64-lane) shuffle reduction
#pragma unroll
    for (int off = 32; off > 0; off >>= 1) {
        lsum += __shfl_down(lsum, off, 64);
        lcnt += __shfl_down(lcnt, off, 64);
    }

    __shared__ float ssum[TPB / 64], scnt[TPB / 64];
    const int lane = threadIdx.x & 63;
    const int wave = threadIdx.x >> 6;
    if (lane == 0) { ssum[wave] = lsum; scnt[wave] = lcnt; }
    __syncthreads();
    if (threadIdx.x == 0) {
        float bs = 0.f, bc = 0.f;
#pragma unroll
        for (int w = 0; w < TPB / 64; ++w) { bs += ssum[w]; bc += scnt[w]; }
        partial[blockIdx.x] = make_float2(bs, bc);   // unconditional write: no init needed
    }
}

__global__ __launch_bounds__(256) void sce_final(const float2* __restrict__ partial,
                                                 float* __restrict__ out) {
    float s = 0.f, c = 0.f;
#pragma unroll
    for (int i = threadIdx.x; i < NBLK; i += 256) {
        float2 p = partial[i];
        s += p.x; c += p.y;
    }
#pragma unroll
    for (int off = 32; off > 0; off >>= 1) {
        s += __shfl_down(s, off, 64);
        c += __shfl_down(c, off, 64);
    }
    __shared__ float ss[4], sc[4];
    const int lane = threadIdx.x & 63;
    const int wave = threadIdx.x >> 6;
    if (lane == 0) { ss[wave] = s; sc[wave] = c; }
    __syncthreads();
    if (threadIdx.x == 0) {
        float bs = 0.f, bc = 0.f;
#pragma unroll
        for (int w = 0; w < 4; ++w) { bs += ss[w]; bc += sc[w]; }
        out[0] = bs / bc;
    }
}

extern "C" void kernel_launch(void* const* d_in, const int* in_sizes, int n_in,
                              void* d_out, int out_size, void* d_ws, size_t ws_size,
                              hipStream_t stream) {
    const float* sim = (const float*)d_in[0];
    const float* gt  = (const float*)d_in[1];
    float2* partial = (float2*)d_ws;                 // 1024 * 8 B = 8 KiB of ws
    sce_main<<<NBLK, TPB, 0, stream>>>(sim, gt, partial);
    sce_final<<<1, 256, 0, stream>>>(partial, (float*)d_out);
}